// Round 6
// baseline (369.788 us; speedup 1.0000x reference)
//
#include <hip/hip_runtime.h>
#include <math.h>

#define BT 32768   // B*T
#define NC 448     // n_embd
#define NH 64      // head_size
#define TT 2048    // T

typedef __bf16 bf16x8 __attribute__((ext_vector_type(8)));
typedef float  f32x4  __attribute__((ext_vector_type(4)));

// fp32 -> bf16 (RNE)
__device__ __forceinline__ unsigned short f2bf(float f) {
  unsigned u = __builtin_bit_cast(unsigned, f);
  return (unsigned short)((u + 0x7FFFu + ((u >> 16) & 1u)) >> 16);
}
__device__ __forceinline__ ushort4 f2bf4(float4 v) {
  ushort4 b; b.x = f2bf(v.x); b.y = f2bf(v.y); b.z = f2bf(v.z); b.w = f2bf(v.w);
  return b;
}

// Swizzled 64x64 bf16 tile: element (row, c) at row*64 + (((c>>3) ^ (row&7))<<3) + (c&7)

// ============ projection ============ (round-4 version + split-K counter zeroing)
__global__ __launch_bounds__(256) void proj_kernel(
    const float* __restrict__ x, const float* __restrict__ Wk,
    const float* __restrict__ Wq, const float* __restrict__ Wv,
    unsigned short* __restrict__ kws, unsigned short* __restrict__ qws,
    unsigned short* __restrict__ vws, int* __restrict__ cnt)
{
  __shared__ unsigned short xs[2][4096];
  __shared__ unsigned short wsm[2][4096];
  const int tid = threadIdx.x;
  const int w = tid >> 6, lane = tid & 63;
  const int q = lane >> 4, l15 = lane & 15;
  const int r0 = blockIdx.x * 64;
  const int p = blockIdx.y;
  const float* W = (p == 0) ? Wk : ((p == 1) ? Wq : Wv);

  // zero the 384 split-K fan-in counters (visible to attn via kernel-boundary flush)
  if (p == 0 && blockIdx.x < 2) {
    int idx = blockIdx.x * 256 + tid;
    if (idx < 384) cnt[idx] = 0;
  }

  f32x4 acc[4];
#pragma unroll
  for (int i = 0; i < 4; ++i) acc[i] = f32x4{0.f, 0.f, 0.f, 0.f};

  const int c0 = (tid & 15) * 4, r_ = tid >> 4;

  float4 xr[4], wr[4];
#pragma unroll
  for (int i = 0; i < 4; ++i) {
    xr[i] = *(const float4*)&x[(size_t)(r0 + r_ + 16 * i) * NC + c0];
    wr[i] = *(const float4*)&W[(size_t)(r_ + 16 * i) * NC + c0];
  }

  for (int ch = 0; ch < 7; ++ch) {
    const int cur = ch & 1;
#pragma unroll
    for (int i = 0; i < 4; ++i) {
      int r = r_ + 16 * i;
      int off = r * 64 + (((c0 >> 3) ^ (r & 7)) << 3) + (c0 & 7);
      *(ushort4*)&xs[cur][off]  = f2bf4(xr[i]);
      *(ushort4*)&wsm[cur][off] = f2bf4(wr[i]);
    }
    __syncthreads();
    if (ch < 6) {
      int kc = (ch + 1) * 64;
#pragma unroll
      for (int i = 0; i < 4; ++i) {
        xr[i] = *(const float4*)&x[(size_t)(r0 + r_ + 16 * i) * NC + kc + c0];
        wr[i] = *(const float4*)&W[(size_t)(r_ + 16 * i) * NC + kc + c0];
      }
    }
#pragma unroll
    for (int ks = 0; ks < 2; ++ks) {
      int xrow = w * 16 + l15;
      int g = q + 4 * ks;
      bf16x8 xf = *(const bf16x8*)&xs[cur][xrow * 64 + ((g ^ (xrow & 7)) << 3)];
#pragma unroll
      for (int t = 0; t < 4; ++t) {
        int wrow = t * 16 + l15;
        bf16x8 wf = *(const bf16x8*)&wsm[cur][wrow * 64 + ((g ^ (wrow & 7)) << 3)];
        if (p == 0)
          acc[t] = __builtin_amdgcn_mfma_f32_16x16x32_bf16(wf, xf, acc[t], 0, 0, 0);
        else
          acc[t] = __builtin_amdgcn_mfma_f32_16x16x32_bf16(xf, wf, acc[t], 0, 0, 0);
      }
    }
  }

  const size_t tile = (size_t)blockIdx.x * 4096;
  if (p == 0) {
#pragma unroll
    for (int t = 0; t < 4; ++t) {
      int j = w * 16 + l15;
      ushort4 bb; bb.x = f2bf(acc[t][0]); bb.y = f2bf(acc[t][1]);
      bb.z = f2bf(acc[t][2]); bb.w = f2bf(acc[t][3]);
      *(ushort4*)&kws[tile + j * 64 + (((2 * t + (q >> 1)) ^ (j & 7)) << 3) + ((q & 1) << 2)] = bb;
    }
  } else if (p == 1) {
    const float qs = 0.068161075f;   // log2(e)/sqrt(448)
#pragma unroll
    for (int t = 0; t < 4; ++t) {
      int h = t * 16 + l15;
#pragma unroll
      for (int rr = 0; rr < 4; ++rr) {
        int R = r0 + w * 16 + q * 4 + rr;
        qws[(size_t)R * 64 + h] = f2bf(acc[t][rr] * qs);
      }
    }
  } else {
#pragma unroll
    for (int t = 0; t < 4; ++t) {
      int h = t * 16 + l15;
      ushort4 bb; bb.x = f2bf(acc[t][0]); bb.y = f2bf(acc[t][1]);
      bb.z = f2bf(acc[t][2]); bb.w = f2bf(acc[t][3]);
      *(ushort4*)&vws[tile + h * 64 + (((2 * w + (q >> 1)) ^ (h & 7)) << 3) + ((q & 1) << 2)] = bb;
    }
  }
}

// ============ flash attention, split-K (8 k-tiles/chunk) + fused combine ============
// grid (80,16). bx decode:
//   [0,16)  : qt = 8+(bx>>1),  chunk c = bx&1        (qt 8..15, 2 chunks)
//   [16,40) : qt = 16+(bx-16)/3, c = (bx-16)%3       (qt 16..23, 3 chunks)
//   [40,72) : qt = 24+((bx-40)>>2), c = (bx-40)&3    (qt 24..31, 4 chunks)
//   [72,80) : qt = 79-bx, direct (single full chunk) (qt 7..0)
// Chunk c covers kt [8c, min(8c+8, qt+1)). Partials: unnormalized O + m/l.
// Last-arriving chunk (device-scope atomic fan-in) merges and writes out.
__global__ __launch_bounds__(256) void attn_partial(
    const unsigned short* __restrict__ kws, const unsigned short* __restrict__ qws,
    const unsigned short* __restrict__ vws, float* __restrict__ out,
    float* __restrict__ opart, float* __restrict__ mlpart, int* __restrict__ cnt)
{
  __shared__ unsigned short ksm[2][4096];
  __shared__ unsigned short vtm[2][4096];
  __shared__ unsigned short psm[4096];
  __shared__ int win;
  const int bx = blockIdx.x, b = blockIdx.y;
  int qt, ci; bool direct;
  if (bx < 16)      { qt = 8 + (bx >> 1);         ci = bx & 1;        direct = false; }
  else if (bx < 40) { qt = 16 + (bx - 16) / 3;    ci = (bx - 16) % 3; direct = false; }
  else if (bx < 72) { qt = 24 + ((bx - 40) >> 2); ci = (bx - 40) & 3; direct = false; }
  else              { qt = 79 - bx;               ci = 0;             direct = true;  }
  const int kt0 = direct ? 0 : ci * 8;
  const int ktn = direct ? (qt + 1) : min(kt0 + 8, qt + 1);
  const int nt = ktn - kt0;

  const int tid = threadIdx.x;
  const int w = tid >> 6, lane = tid & 63;
  const int q = lane >> 4, l15 = lane & 15;
  const int t0 = b * TT + qt * 64;
  const int l7 = l15 & 7;

  bf16x8 qf[2];
#pragma unroll
  for (int ks = 0; ks < 2; ++ks)
    qf[ks] = *(const bf16x8*)&qws[(size_t)(t0 + w * 16 + l15) * 64 + 32 * ks + q * 8];

  f32x4 oacc[4];
#pragma unroll
  for (int ht = 0; ht < 4; ++ht) oacc[ht] = f32x4{0.f, 0.f, 0.f, 0.f};
  float m_i = -INFINITY, l_i = 0.f;   // per-lane, row i = w*16 + l15

  uint4 kr0, kr1, vr0, vr1;
  {
    const unsigned short* kt_ = kws + (size_t)(b * 32 + kt0) * 4096;
    const unsigned short* vt_ = vws + (size_t)(b * 32 + kt0) * 4096;
    kr0 = *(const uint4*)&kt_[tid * 8];  kr1 = *(const uint4*)&kt_[2048 + tid * 8];
    vr0 = *(const uint4*)&vt_[tid * 8];  vr1 = *(const uint4*)&vt_[2048 + tid * 8];
  }

  for (int it = 0; it < nt; ++it) {
    const int kt = kt0 + it;
    const int cur = it & 1;
    *(uint4*)&ksm[cur][tid * 8] = kr0;  *(uint4*)&ksm[cur][2048 + tid * 8] = kr1;
    *(uint4*)&vtm[cur][tid * 8] = vr0;  *(uint4*)&vtm[cur][2048 + tid * 8] = vr1;
    __syncthreads();
    if (it + 1 < nt) {
      const unsigned short* kt_ = kws + (size_t)(b * 32 + kt + 1) * 4096;
      const unsigned short* vt_ = vws + (size_t)(b * 32 + kt + 1) * 4096;
      kr0 = *(const uint4*)&kt_[tid * 8];  kr1 = *(const uint4*)&kt_[2048 + tid * 8];
      vr0 = *(const uint4*)&vt_[tid * 8];  vr1 = *(const uint4*)&vt_[2048 + tid * 8];
    }

    // S^T = K . Q^T : lane j = jt*16+q*4+rr, i = l15
    f32x4 sacc[4];
#pragma unroll
    for (int jt = 0; jt < 4; ++jt) sacc[jt] = f32x4{0.f, 0.f, 0.f, 0.f};
#pragma unroll
    for (int jt = 0; jt < 4; ++jt) {
      int j = jt * 16 + l15;
#pragma unroll
      for (int ks = 0; ks < 2; ++ks) {
        bf16x8 kf = *(const bf16x8*)&ksm[cur][j * 64 + (((q + 4 * ks) ^ (j & 7)) << 3)];
        sacc[jt] = __builtin_amdgcn_mfma_f32_16x16x32_bf16(kf, qf[ks], sacc[jt], 0, 0, 0);
      }
    }

    if (kt == qt) {   // diagonal tile: mask j > i
      int iloc = w * 16 + l15;
#pragma unroll
      for (int jt = 0; jt < 4; ++jt)
#pragma unroll
        for (int rr = 0; rr < 4; ++rr)
          if (jt * 16 + q * 4 + rr > iloc) sacc[jt][rr] = -INFINITY;
    }

    // online softmax (per-lane row state)
    float mx = -INFINITY;
#pragma unroll
    for (int jt = 0; jt < 4; ++jt)
#pragma unroll
      for (int rr = 0; rr < 4; ++rr) mx = fmaxf(mx, sacc[jt][rr]);
    mx = fmaxf(mx, __shfl_xor(mx, 16));
    mx = fmaxf(mx, __shfl_xor(mx, 32));
    float mn = fmaxf(m_i, mx);
    float alpha = exp2f(m_i - mn);
    m_i = mn;
    float p[4][4], rs = 0.f;
#pragma unroll
    for (int jt = 0; jt < 4; ++jt)
#pragma unroll
      for (int rr = 0; rr < 4; ++rr) {
        float pv = exp2f(sacc[jt][rr] - mn);
        p[jt][rr] = pv; rs += pv;
      }
    rs += __shfl_xor(rs, 16);
    rs += __shfl_xor(rs, 32);
    l_i = l_i * alpha + rs;

    float a_t[4];
#pragma unroll
    for (int rr = 0; rr < 4; ++rr) a_t[rr] = __shfl(alpha, q * 4 + rr);
#pragma unroll
    for (int ht = 0; ht < 4; ++ht)
#pragma unroll
      for (int rr = 0; rr < 4; ++rr) oacc[ht][rr] *= a_t[rr];

    // P -> LDS (wave-private rows)
    {
      int row = w * 16 + l15;
#pragma unroll
      for (int jt = 0; jt < 4; ++jt) {
        ushort4 bb; bb.x = f2bf(p[jt][0]); bb.y = f2bf(p[jt][1]);
        bb.z = f2bf(p[jt][2]); bb.w = f2bf(p[jt][3]);
        *(ushort4*)&psm[row * 64 + (((2 * jt + (q >> 1)) ^ l7) << 3) + ((q & 1) << 2)] = bb;
      }
    }

    // O += P . V
#pragma unroll
    for (int ks2 = 0; ks2 < 2; ++ks2) {
      int prow = w * 16 + l15;
      bf16x8 pf = *(const bf16x8*)&psm[prow * 64 + (((q + 4 * ks2) ^ l7) << 3)];
#pragma unroll
      for (int ht = 0; ht < 4; ++ht) {
        int h = ht * 16 + l15;
        bf16x8 vf = *(const bf16x8*)&vtm[cur][h * 64 + (((q + 4 * ks2) ^ l7) << 3)];
        oacc[ht] = __builtin_amdgcn_mfma_f32_16x16x32_bf16(pf, vf, oacc[ht], 0, 0, 0);
      }
    }
  }

  if (direct) {
    float l_t[4];
#pragma unroll
    for (int rr = 0; rr < 4; ++rr) l_t[rr] = __shfl(l_i, q * 4 + rr);
#pragma unroll
    for (int rr = 0; rr < 4; ++rr) {
      float inv = 1.f / l_t[rr];
      int R = t0 + w * 16 + q * 4 + rr;
#pragma unroll
      for (int ht = 0; ht < 4; ++ht)
        out[(size_t)R * 64 + ht * 16 + l15] = oacc[ht][rr] * inv;
    }
    return;
  }

  // ---- partial store + atomic fan-in combine ----
  const int qi = qt - 8;                 // 0..23
  const int nch = (qt >> 3) + 1;         // 2..4 chunks
  const size_t sbase = (size_t)(b * 24 + qi) * 4;
  {
    float* Op = opart + (sbase + ci) * 4096;
#pragma unroll
    for (int rr = 0; rr < 4; ++rr) {
      int rloc = w * 16 + q * 4 + rr;
#pragma unroll
      for (int ht = 0; ht < 4; ++ht)
        Op[rloc * 64 + ht * 16 + l15] = oacc[ht][rr];
    }
    if (q == 0) {
      mlpart[(sbase + ci) * 128 + w * 16 + l15]      = m_i;
      mlpart[(sbase + ci) * 128 + 64 + w * 16 + l15] = l_i;
    }
  }
  __threadfence();          // release: make this block's partials visible device-wide
  __syncthreads();          // order ALL threads' fences before the atomic
  if (tid == 0) win = (atomicAdd(&cnt[b * 24 + qi], 1) == nch - 1);
  __syncthreads();
  if (!win) return;

  __threadfence();          // acquire: invalidate stale L2 lines before reading peers
  const int r = tid >> 2, cc = (tid & 3) * 16;
  float mc[4], lc[4];
  float mm = -INFINITY;
#pragma unroll 4
  for (int c = 0; c < nch; ++c) {
    mc[c] = mlpart[(sbase + c) * 128 + r];
    lc[c] = mlpart[(sbase + c) * 128 + 64 + r];
    mm = fmaxf(mm, mc[c]);
  }
  float denom = 0.f, wgt[4];
#pragma unroll 4
  for (int c = 0; c < nch; ++c) { wgt[c] = exp2f(mc[c] - mm); denom += wgt[c] * lc[c]; }
  const float inv = 1.f / denom;
  float* op = out + (size_t)(t0 + r) * 64;
#pragma unroll
  for (int j = 0; j < 4; ++j) {
    float4 acc4 = make_float4(0.f, 0.f, 0.f, 0.f);
#pragma unroll 4
    for (int c = 0; c < nch; ++c) {
      float wc = wgt[c] * inv;
      float4 a = *(const float4*)&opart[(sbase + c) * 4096 + r * 64 + cc + j * 4];
      acc4.x += wc * a.x; acc4.y += wc * a.y; acc4.z += wc * a.z; acc4.w += wc * a.w;
    }
    *(float4*)&op[cc + j * 4] = acc4;
  }
}

extern "C" void kernel_launch(void* const* d_in, const int* in_sizes, int n_in,
                              void* d_out, int out_size, void* d_ws, size_t ws_size,
                              hipStream_t stream) {
  const float* x  = (const float*)d_in[0];
  const float* Wk = (const float*)d_in[1];
  const float* Wq = (const float*)d_in[2];
  const float* Wv = (const float*)d_in[3];
  unsigned short* kws = (unsigned short*)d_ws;            // 4.19 MB
  unsigned short* qws = kws + (size_t)BT * NH;            // 4.19 MB
  unsigned short* vws = qws + (size_t)BT * NH;            // 4.19 MB
  float* opart  = (float*)(vws + (size_t)BT * NH);        // 1536 slots * 16 KB = 25.2 MB
  float* mlpart = opart + (size_t)1536 * 4096;            // 786 KB
  int*   cnt    = (int*)(mlpart + (size_t)1536 * 128);    // 384 ints   (total ~38.5 MB)
  float* out = (float*)d_out;

  proj_kernel<<<dim3(512, 3), 256, 0, stream>>>(x, Wk, Wq, Wv, kws, qws, vws, cnt);
  attn_partial<<<dim3(80, 16), 256, 0, stream>>>(kws, qws, vws, out, opart, mlpart, cnt);
}

// Round 7
// 150.723 us; speedup vs baseline: 2.4534x; 2.4534x over previous
//
#include <hip/hip_runtime.h>
#include <math.h>

#define BT 32768   // B*T
#define NC 448     // n_embd
#define NH 64      // head_size
#define TT 2048    // T

typedef __bf16 bf16x8 __attribute__((ext_vector_type(8)));
typedef float  f32x4  __attribute__((ext_vector_type(4)));

// fp32 -> bf16 (RNE)
__device__ __forceinline__ unsigned short f2bf(float f) {
  unsigned u = __builtin_bit_cast(unsigned, f);
  return (unsigned short)((u + 0x7FFFu + ((u >> 16) & 1u)) >> 16);
}
__device__ __forceinline__ ushort4 f2bf4(float4 v) {
  ushort4 b; b.x = f2bf(v.x); b.y = f2bf(v.y); b.z = f2bf(v.z); b.w = f2bf(v.w);
  return b;
}

// Swizzled 64x64 bf16 tile: element (row, c) at row*64 + (((c>>3) ^ (row&7))<<3) + (c&7)

// ============ projection ============ (round-4/5 verified version)
__global__ __launch_bounds__(256) void proj_kernel(
    const float* __restrict__ x, const float* __restrict__ Wk,
    const float* __restrict__ Wq, const float* __restrict__ Wv,
    unsigned short* __restrict__ kws, unsigned short* __restrict__ qws,
    unsigned short* __restrict__ vws)
{
  __shared__ unsigned short xs[2][4096];
  __shared__ unsigned short wsm[2][4096];
  const int tid = threadIdx.x;
  const int w = tid >> 6, lane = tid & 63;
  const int q = lane >> 4, l15 = lane & 15;
  const int r0 = blockIdx.x * 64;
  const int p = blockIdx.y;
  const float* W = (p == 0) ? Wk : ((p == 1) ? Wq : Wv);

  f32x4 acc[4];
#pragma unroll
  for (int i = 0; i < 4; ++i) acc[i] = f32x4{0.f, 0.f, 0.f, 0.f};

  const int c0 = (tid & 15) * 4, r_ = tid >> 4;

  float4 xr[4], wr[4];
#pragma unroll
  for (int i = 0; i < 4; ++i) {
    xr[i] = *(const float4*)&x[(size_t)(r0 + r_ + 16 * i) * NC + c0];
    wr[i] = *(const float4*)&W[(size_t)(r_ + 16 * i) * NC + c0];
  }

  for (int ch = 0; ch < 7; ++ch) {
    const int cur = ch & 1;
#pragma unroll
    for (int i = 0; i < 4; ++i) {
      int r = r_ + 16 * i;
      int off = r * 64 + (((c0 >> 3) ^ (r & 7)) << 3) + (c0 & 7);
      *(ushort4*)&xs[cur][off]  = f2bf4(xr[i]);
      *(ushort4*)&wsm[cur][off] = f2bf4(wr[i]);
    }
    __syncthreads();
    if (ch < 6) {
      int kc = (ch + 1) * 64;
#pragma unroll
      for (int i = 0; i < 4; ++i) {
        xr[i] = *(const float4*)&x[(size_t)(r0 + r_ + 16 * i) * NC + kc + c0];
        wr[i] = *(const float4*)&W[(size_t)(r_ + 16 * i) * NC + kc + c0];
      }
    }
#pragma unroll
    for (int ks = 0; ks < 2; ++ks) {
      int xrow = w * 16 + l15;
      int g = q + 4 * ks;
      bf16x8 xf = *(const bf16x8*)&xs[cur][xrow * 64 + ((g ^ (xrow & 7)) << 3)];
#pragma unroll
      for (int t = 0; t < 4; ++t) {
        int wrow = t * 16 + l15;
        bf16x8 wf = *(const bf16x8*)&wsm[cur][wrow * 64 + ((g ^ (wrow & 7)) << 3)];
        if (p == 0)
          acc[t] = __builtin_amdgcn_mfma_f32_16x16x32_bf16(wf, xf, acc[t], 0, 0, 0);
        else
          acc[t] = __builtin_amdgcn_mfma_f32_16x16x32_bf16(xf, wf, acc[t], 0, 0, 0);
      }
    }
  }

  const size_t tile = (size_t)blockIdx.x * 4096;
  if (p == 0) {
#pragma unroll
    for (int t = 0; t < 4; ++t) {
      int j = w * 16 + l15;
      ushort4 bb; bb.x = f2bf(acc[t][0]); bb.y = f2bf(acc[t][1]);
      bb.z = f2bf(acc[t][2]); bb.w = f2bf(acc[t][3]);
      *(ushort4*)&kws[tile + j * 64 + (((2 * t + (q >> 1)) ^ (j & 7)) << 3) + ((q & 1) << 2)] = bb;
    }
  } else if (p == 1) {
    const float qs = 0.068161075f;   // log2(e)/sqrt(448)
#pragma unroll
    for (int t = 0; t < 4; ++t) {
      int h = t * 16 + l15;
#pragma unroll
      for (int rr = 0; rr < 4; ++rr) {
        int R = r0 + w * 16 + q * 4 + rr;
        qws[(size_t)R * 64 + h] = f2bf(acc[t][rr] * qs);
      }
    }
  } else {
#pragma unroll
    for (int t = 0; t < 4; ++t) {
      int h = t * 16 + l15;
      ushort4 bb; bb.x = f2bf(acc[t][0]); bb.y = f2bf(acc[t][1]);
      bb.z = f2bf(acc[t][2]); bb.w = f2bf(acc[t][3]);
      *(ushort4*)&vws[tile + h * 64 + (((2 * w + (q >> 1)) ^ (h & 7)) << 3) + ((q & 1) << 2)] = bb;
    }
  }
}

// ============ flash attention, split-K (8 k-tiles/chunk), NO fan-in ============
// grid (80,16). bx decode (longest chunks first, direct short blocks last):
//   [0,16)  : qt = 8+(bx>>1),  ci = bx&1            (qt 8..15, 2 chunks)
//   [16,40) : qt = 16+(bx-16)/3, ci = (bx-16)%3     (qt 16..23, 3 chunks)
//   [40,72) : qt = 24+((bx-40)>>2), ci = (bx-40)&3  (qt 24..31, 4 chunks)
//   [72,80) : qt = 79-bx, direct single chunk       (qt 7..0 -> out directly)
// Chunk ci covers kt [8ci, min(8ci+8, qt+1)); partials = unnormalized O + m/l.
// combine_kernel (separate launch = one implicit device-wide flush) merges.
__global__ __launch_bounds__(256) void attn_partial(
    const unsigned short* __restrict__ kws, const unsigned short* __restrict__ qws,
    const unsigned short* __restrict__ vws, float* __restrict__ out,
    float* __restrict__ opart, float* __restrict__ mlpart)
{
  __shared__ unsigned short ksm[2][4096];
  __shared__ unsigned short vtm[2][4096];
  __shared__ unsigned short psm[4096];
  const int bx = blockIdx.x, b = blockIdx.y;
  int qt, ci; bool direct;
  if (bx < 16)      { qt = 8 + (bx >> 1);         ci = bx & 1;        direct = false; }
  else if (bx < 40) { qt = 16 + (bx - 16) / 3;    ci = (bx - 16) % 3; direct = false; }
  else if (bx < 72) { qt = 24 + ((bx - 40) >> 2); ci = (bx - 40) & 3; direct = false; }
  else              { qt = 79 - bx;               ci = 0;             direct = true;  }
  const int kt0 = direct ? 0 : ci * 8;
  const int ktn = direct ? (qt + 1) : min(kt0 + 8, qt + 1);
  const int nt = ktn - kt0;

  const int tid = threadIdx.x;
  const int w = tid >> 6, lane = tid & 63;
  const int q = lane >> 4, l15 = lane & 15;
  const int t0 = b * TT + qt * 64;
  const int l7 = l15 & 7;

  bf16x8 qf[2];
#pragma unroll
  for (int ks = 0; ks < 2; ++ks)
    qf[ks] = *(const bf16x8*)&qws[(size_t)(t0 + w * 16 + l15) * 64 + 32 * ks + q * 8];

  f32x4 oacc[4];
#pragma unroll
  for (int ht = 0; ht < 4; ++ht) oacc[ht] = f32x4{0.f, 0.f, 0.f, 0.f};
  float m_i = -INFINITY, l_i = 0.f;   // per-lane, row i = w*16 + l15

  uint4 kr0, kr1, vr0, vr1;
  {
    const unsigned short* kt_ = kws + (size_t)(b * 32 + kt0) * 4096;
    const unsigned short* vt_ = vws + (size_t)(b * 32 + kt0) * 4096;
    kr0 = *(const uint4*)&kt_[tid * 8];  kr1 = *(const uint4*)&kt_[2048 + tid * 8];
    vr0 = *(const uint4*)&vt_[tid * 8];  vr1 = *(const uint4*)&vt_[2048 + tid * 8];
  }

  for (int it = 0; it < nt; ++it) {
    const int kt = kt0 + it;
    const int cur = it & 1;
    *(uint4*)&ksm[cur][tid * 8] = kr0;  *(uint4*)&ksm[cur][2048 + tid * 8] = kr1;
    *(uint4*)&vtm[cur][tid * 8] = vr0;  *(uint4*)&vtm[cur][2048 + tid * 8] = vr1;
    __syncthreads();
    if (it + 1 < nt) {
      const unsigned short* kt_ = kws + (size_t)(b * 32 + kt + 1) * 4096;
      const unsigned short* vt_ = vws + (size_t)(b * 32 + kt + 1) * 4096;
      kr0 = *(const uint4*)&kt_[tid * 8];  kr1 = *(const uint4*)&kt_[2048 + tid * 8];
      vr0 = *(const uint4*)&vt_[tid * 8];  vr1 = *(const uint4*)&vt_[2048 + tid * 8];
    }

    // S^T = K . Q^T : lane j = jt*16+q*4+rr, i = l15
    f32x4 sacc[4];
#pragma unroll
    for (int jt = 0; jt < 4; ++jt) sacc[jt] = f32x4{0.f, 0.f, 0.f, 0.f};
#pragma unroll
    for (int jt = 0; jt < 4; ++jt) {
      int j = jt * 16 + l15;
#pragma unroll
      for (int ks = 0; ks < 2; ++ks) {
        bf16x8 kf = *(const bf16x8*)&ksm[cur][j * 64 + (((q + 4 * ks) ^ (j & 7)) << 3)];
        sacc[jt] = __builtin_amdgcn_mfma_f32_16x16x32_bf16(kf, qf[ks], sacc[jt], 0, 0, 0);
      }
    }

    if (kt == qt) {   // diagonal tile: mask j > i
      int iloc = w * 16 + l15;
#pragma unroll
      for (int jt = 0; jt < 4; ++jt)
#pragma unroll
        for (int rr = 0; rr < 4; ++rr)
          if (jt * 16 + q * 4 + rr > iloc) sacc[jt][rr] = -INFINITY;
    }

    // online softmax (per-lane row state)
    float mx = -INFINITY;
#pragma unroll
    for (int jt = 0; jt < 4; ++jt)
#pragma unroll
      for (int rr = 0; rr < 4; ++rr) mx = fmaxf(mx, sacc[jt][rr]);
    mx = fmaxf(mx, __shfl_xor(mx, 16));
    mx = fmaxf(mx, __shfl_xor(mx, 32));
    float mn = fmaxf(m_i, mx);
    float alpha = exp2f(m_i - mn);
    m_i = mn;
    float p[4][4], rs = 0.f;
#pragma unroll
    for (int jt = 0; jt < 4; ++jt)
#pragma unroll
      for (int rr = 0; rr < 4; ++rr) {
        float pv = exp2f(sacc[jt][rr] - mn);
        p[jt][rr] = pv; rs += pv;
      }
    rs += __shfl_xor(rs, 16);
    rs += __shfl_xor(rs, 32);
    l_i = l_i * alpha + rs;

    float a_t[4];
#pragma unroll
    for (int rr = 0; rr < 4; ++rr) a_t[rr] = __shfl(alpha, q * 4 + rr);
#pragma unroll
    for (int ht = 0; ht < 4; ++ht)
#pragma unroll
      for (int rr = 0; rr < 4; ++rr) oacc[ht][rr] *= a_t[rr];

    // P -> LDS (wave-private rows)
    {
      int row = w * 16 + l15;
#pragma unroll
      for (int jt = 0; jt < 4; ++jt) {
        ushort4 bb; bb.x = f2bf(p[jt][0]); bb.y = f2bf(p[jt][1]);
        bb.z = f2bf(p[jt][2]); bb.w = f2bf(p[jt][3]);
        *(ushort4*)&psm[row * 64 + (((2 * jt + (q >> 1)) ^ l7) << 3) + ((q & 1) << 2)] = bb;
      }
    }

    // O += P . V
#pragma unroll
    for (int ks2 = 0; ks2 < 2; ++ks2) {
      int prow = w * 16 + l15;
      bf16x8 pf = *(const bf16x8*)&psm[prow * 64 + (((q + 4 * ks2) ^ l7) << 3)];
#pragma unroll
      for (int ht = 0; ht < 4; ++ht) {
        int h = ht * 16 + l15;
        bf16x8 vf = *(const bf16x8*)&vtm[cur][h * 64 + (((q + 4 * ks2) ^ l7) << 3)];
        oacc[ht] = __builtin_amdgcn_mfma_f32_16x16x32_bf16(pf, vf, oacc[ht], 0, 0, 0);
      }
    }
  }

  if (direct) {
    float l_t[4];
#pragma unroll
    for (int rr = 0; rr < 4; ++rr) l_t[rr] = __shfl(l_i, q * 4 + rr);
#pragma unroll
    for (int rr = 0; rr < 4; ++rr) {
      float inv = 1.f / l_t[rr];
      int R = t0 + w * 16 + q * 4 + rr;
#pragma unroll
      for (int ht = 0; ht < 4; ++ht)
        out[(size_t)R * 64 + ht * 16 + l15] = oacc[ht][rr] * inv;
    }
  } else {
    const size_t slot = (size_t)(b * 24 + (qt - 8)) * 4 + ci;
    float* Op = opart + slot * 4096;
#pragma unroll
    for (int rr = 0; rr < 4; ++rr) {
      int rloc = w * 16 + q * 4 + rr;
#pragma unroll
      for (int ht = 0; ht < 4; ++ht)
        Op[rloc * 64 + ht * 16 + l15] = oacc[ht][rr];
    }
    if (q == 0) {
      mlpart[slot * 128 + w * 16 + l15]      = m_i;
      mlpart[slot * 128 + 64 + w * 16 + l15] = l_i;
    }
  }
}

// ============ combine: merge 2-4 partials for qt in [8,32) ============
__global__ __launch_bounds__(256) void combine_kernel(
    const float* __restrict__ opart, const float* __restrict__ mlpart,
    float* __restrict__ out)
{
  const int qi = blockIdx.x, b = blockIdx.y;   // qi 0..23 -> qt 8..31
  const int qt = 8 + qi;
  const int nch = (qt >> 3) + 1;               // 2..4 chunks
  const size_t sbase = (size_t)(b * 24 + qi) * 4;
  const int t = threadIdx.x;
  const int r = t >> 2, c0 = (t & 3) * 16;

  float mc[4], lc[4], mm = -INFINITY;
#pragma unroll 4
  for (int c = 0; c < nch; ++c) {
    mc[c] = mlpart[(sbase + c) * 128 + r];
    lc[c] = mlpart[(sbase + c) * 128 + 64 + r];
    mm = fmaxf(mm, mc[c]);
  }
  float denom = 0.f, wgt[4];
#pragma unroll 4
  for (int c = 0; c < nch; ++c) { wgt[c] = exp2f(mc[c] - mm); denom += wgt[c] * lc[c]; }
  const float inv = 1.f / denom;

  float* op = out + (size_t)(b * TT + qt * 64 + r) * 64;
#pragma unroll
  for (int j = 0; j < 4; ++j) {
    float4 acc4 = make_float4(0.f, 0.f, 0.f, 0.f);
#pragma unroll 4
    for (int c = 0; c < nch; ++c) {
      float wc = wgt[c] * inv;
      float4 a = *(const float4*)&opart[(sbase + c) * 4096 + r * 64 + c0 + j * 4];
      acc4.x += wc * a.x; acc4.y += wc * a.y; acc4.z += wc * a.z; acc4.w += wc * a.w;
    }
    *(float4*)&op[c0 + j * 4] = acc4;
  }
}

extern "C" void kernel_launch(void* const* d_in, const int* in_sizes, int n_in,
                              void* d_out, int out_size, void* d_ws, size_t ws_size,
                              hipStream_t stream) {
  const float* x  = (const float*)d_in[0];
  const float* Wk = (const float*)d_in[1];
  const float* Wq = (const float*)d_in[2];
  const float* Wv = (const float*)d_in[3];
  unsigned short* kws = (unsigned short*)d_ws;          // 4.19 MB
  unsigned short* qws = kws + (size_t)BT * NH;          // 4.19 MB
  unsigned short* vws = qws + (size_t)BT * NH;          // 4.19 MB
  float* opart  = (float*)(vws + (size_t)BT * NH);      // 1536 slots * 16 KB = 25.2 MB
  float* mlpart = opart + (size_t)1536 * 4096;          // 786 KB  (total ~38.5 MB)
  float* out = (float*)d_out;

  proj_kernel<<<dim3(512, 3), 256, 0, stream>>>(x, Wk, Wq, Wv, kws, qws, vws);
  attn_partial<<<dim3(80, 16), 256, 0, stream>>>(kws, qws, vws, out, opart, mlpart);
  combine_kernel<<<dim3(24, 16), 256, 0, stream>>>(opart, mlpart, out);
}

// Round 8
// 146.463 us; speedup vs baseline: 2.5248x; 1.0291x over previous
//
#include <hip/hip_runtime.h>
#include <math.h>

#define BT 32768   // B*T
#define NC 448     // n_embd
#define NH 64      // head_size
#define TT 2048    // T

typedef __bf16 bf16x8 __attribute__((ext_vector_type(8)));
typedef float  f32x4  __attribute__((ext_vector_type(4)));

// fp32 -> bf16 (RNE)
__device__ __forceinline__ unsigned short f2bf(float f) {
  unsigned u = __builtin_bit_cast(unsigned, f);
  return (unsigned short)((u + 0x7FFFu + ((u >> 16) & 1u)) >> 16);
}
__device__ __forceinline__ ushort4 f2bf4(float4 v) {
  ushort4 b; b.x = f2bf(v.x); b.y = f2bf(v.y); b.z = f2bf(v.z); b.w = f2bf(v.w);
  return b;
}
__device__ __forceinline__ float bf2f(unsigned short u) {
  return __builtin_bit_cast(float, (unsigned)u << 16);
}

// Swizzled 64x64 bf16 tile: element (row, c) at row*64 + (((c>>3) ^ (row&7))<<3) + (c&7)

// ============ projection ============ (round-4/5 verified version)
__global__ __launch_bounds__(256) void proj_kernel(
    const float* __restrict__ x, const float* __restrict__ Wk,
    const float* __restrict__ Wq, const float* __restrict__ Wv,
    unsigned short* __restrict__ kws, unsigned short* __restrict__ qws,
    unsigned short* __restrict__ vws)
{
  __shared__ unsigned short xs[2][4096];
  __shared__ unsigned short wsm[2][4096];
  const int tid = threadIdx.x;
  const int w = tid >> 6, lane = tid & 63;
  const int q = lane >> 4, l15 = lane & 15;
  const int r0 = blockIdx.x * 64;
  const int p = blockIdx.y;
  const float* W = (p == 0) ? Wk : ((p == 1) ? Wq : Wv);

  f32x4 acc[4];
#pragma unroll
  for (int i = 0; i < 4; ++i) acc[i] = f32x4{0.f, 0.f, 0.f, 0.f};

  const int c0 = (tid & 15) * 4, r_ = tid >> 4;

  float4 xr[4], wr[4];
#pragma unroll
  for (int i = 0; i < 4; ++i) {
    xr[i] = *(const float4*)&x[(size_t)(r0 + r_ + 16 * i) * NC + c0];
    wr[i] = *(const float4*)&W[(size_t)(r_ + 16 * i) * NC + c0];
  }

  for (int ch = 0; ch < 7; ++ch) {
    const int cur = ch & 1;
#pragma unroll
    for (int i = 0; i < 4; ++i) {
      int r = r_ + 16 * i;
      int off = r * 64 + (((c0 >> 3) ^ (r & 7)) << 3) + (c0 & 7);
      *(ushort4*)&xs[cur][off]  = f2bf4(xr[i]);
      *(ushort4*)&wsm[cur][off] = f2bf4(wr[i]);
    }
    __syncthreads();
    if (ch < 6) {
      int kc = (ch + 1) * 64;
#pragma unroll
      for (int i = 0; i < 4; ++i) {
        xr[i] = *(const float4*)&x[(size_t)(r0 + r_ + 16 * i) * NC + kc + c0];
        wr[i] = *(const float4*)&W[(size_t)(r_ + 16 * i) * NC + kc + c0];
      }
    }
#pragma unroll
    for (int ks = 0; ks < 2; ++ks) {
      int xrow = w * 16 + l15;
      int g = q + 4 * ks;
      bf16x8 xf = *(const bf16x8*)&xs[cur][xrow * 64 + ((g ^ (xrow & 7)) << 3)];
#pragma unroll
      for (int t = 0; t < 4; ++t) {
        int wrow = t * 16 + l15;
        bf16x8 wf = *(const bf16x8*)&wsm[cur][wrow * 64 + ((g ^ (wrow & 7)) << 3)];
        if (p == 0)
          acc[t] = __builtin_amdgcn_mfma_f32_16x16x32_bf16(wf, xf, acc[t], 0, 0, 0);
        else
          acc[t] = __builtin_amdgcn_mfma_f32_16x16x32_bf16(xf, wf, acc[t], 0, 0, 0);
      }
    }
  }

  const size_t tile = (size_t)blockIdx.x * 4096;
  if (p == 0) {
#pragma unroll
    for (int t = 0; t < 4; ++t) {
      int j = w * 16 + l15;
      ushort4 bb; bb.x = f2bf(acc[t][0]); bb.y = f2bf(acc[t][1]);
      bb.z = f2bf(acc[t][2]); bb.w = f2bf(acc[t][3]);
      *(ushort4*)&kws[tile + j * 64 + (((2 * t + (q >> 1)) ^ (j & 7)) << 3) + ((q & 1) << 2)] = bb;
    }
  } else if (p == 1) {
    const float qs = 0.068161075f;   // log2(e)/sqrt(448)
#pragma unroll
    for (int t = 0; t < 4; ++t) {
      int h = t * 16 + l15;
#pragma unroll
      for (int rr = 0; rr < 4; ++rr) {
        int R = r0 + w * 16 + q * 4 + rr;
        qws[(size_t)R * 64 + h] = f2bf(acc[t][rr] * qs);
      }
    }
  } else {
#pragma unroll
    for (int t = 0; t < 4; ++t) {
      int h = t * 16 + l15;
      ushort4 bb; bb.x = f2bf(acc[t][0]); bb.y = f2bf(acc[t][1]);
      bb.z = f2bf(acc[t][2]); bb.w = f2bf(acc[t][3]);
      *(ushort4*)&vws[tile + h * 64 + (((2 * w + (q >> 1)) ^ (h & 7)) << 3) + ((q & 1) << 2)] = bb;
    }
  }
}

// ============ flash attention, split-K (round-5 geometry, bf16 partials) ============
// grid (48,16). bx mapping (longest-first):
//   bx<16 : qt=16+bx, kt [0,16), slot 0 (no diagonal)
//   16-31 : qt=47-bx, kt [16,qt+1), slot 1 (has diagonal)
//   32-47 : qt=47-bx, kt [0,qt+1), single chunk -> writes out directly
__global__ __launch_bounds__(256) void attn_partial(
    const unsigned short* __restrict__ kws, const unsigned short* __restrict__ qws,
    const unsigned short* __restrict__ vws, float* __restrict__ out,
    unsigned short* __restrict__ opart, float* __restrict__ mlpart)
{
  __shared__ unsigned short ksm[2][4096];
  __shared__ unsigned short vtm[2][4096];
  __shared__ unsigned short psm[4096];
  const int bx = blockIdx.x, b = blockIdx.y;
  int qt, kt0, ktn, ci; bool direct;
  if (bx < 16)      { qt = 16 + bx; kt0 = 0;  ktn = 16;     ci = 0; direct = false; }
  else if (bx < 32) { qt = 47 - bx; kt0 = 16; ktn = qt + 1; ci = 1; direct = false; }
  else              { qt = 47 - bx; kt0 = 0;  ktn = qt + 1; ci = 0; direct = true;  }
  const int nt = ktn - kt0;

  const int tid = threadIdx.x;
  const int w = tid >> 6, lane = tid & 63;
  const int q = lane >> 4, l15 = lane & 15;
  const int t0 = b * TT + qt * 64;
  const int l7 = l15 & 7;

  bf16x8 qf[2];
#pragma unroll
  for (int ks = 0; ks < 2; ++ks)
    qf[ks] = *(const bf16x8*)&qws[(size_t)(t0 + w * 16 + l15) * 64 + 32 * ks + q * 8];

  f32x4 oacc[4];
#pragma unroll
  for (int ht = 0; ht < 4; ++ht) oacc[ht] = f32x4{0.f, 0.f, 0.f, 0.f};
  float m_i = -INFINITY, l_i = 0.f;   // per-lane, row i = w*16 + l15

  uint4 kr0, kr1, vr0, vr1;
  {
    const unsigned short* kt_ = kws + (size_t)(b * 32 + kt0) * 4096;
    const unsigned short* vt_ = vws + (size_t)(b * 32 + kt0) * 4096;
    kr0 = *(const uint4*)&kt_[tid * 8];  kr1 = *(const uint4*)&kt_[2048 + tid * 8];
    vr0 = *(const uint4*)&vt_[tid * 8];  vr1 = *(const uint4*)&vt_[2048 + tid * 8];
  }

  for (int it = 0; it < nt; ++it) {
    const int kt = kt0 + it;
    const int cur = it & 1;
    *(uint4*)&ksm[cur][tid * 8] = kr0;  *(uint4*)&ksm[cur][2048 + tid * 8] = kr1;
    *(uint4*)&vtm[cur][tid * 8] = vr0;  *(uint4*)&vtm[cur][2048 + tid * 8] = vr1;
    __syncthreads();
    if (it + 1 < nt) {
      const unsigned short* kt_ = kws + (size_t)(b * 32 + kt + 1) * 4096;
      const unsigned short* vt_ = vws + (size_t)(b * 32 + kt + 1) * 4096;
      kr0 = *(const uint4*)&kt_[tid * 8];  kr1 = *(const uint4*)&kt_[2048 + tid * 8];
      vr0 = *(const uint4*)&vt_[tid * 8];  vr1 = *(const uint4*)&vt_[2048 + tid * 8];
    }

    // S^T = K . Q^T : lane j = jt*16+q*4+rr, i = l15
    f32x4 sacc[4];
#pragma unroll
    for (int jt = 0; jt < 4; ++jt) sacc[jt] = f32x4{0.f, 0.f, 0.f, 0.f};
#pragma unroll
    for (int jt = 0; jt < 4; ++jt) {
      int j = jt * 16 + l15;
#pragma unroll
      for (int ks = 0; ks < 2; ++ks) {
        bf16x8 kf = *(const bf16x8*)&ksm[cur][j * 64 + (((q + 4 * ks) ^ (j & 7)) << 3)];
        sacc[jt] = __builtin_amdgcn_mfma_f32_16x16x32_bf16(kf, qf[ks], sacc[jt], 0, 0, 0);
      }
    }

    if (kt == qt) {   // diagonal tile: mask j > i
      int iloc = w * 16 + l15;
#pragma unroll
      for (int jt = 0; jt < 4; ++jt)
#pragma unroll
        for (int rr = 0; rr < 4; ++rr)
          if (jt * 16 + q * 4 + rr > iloc) sacc[jt][rr] = -INFINITY;
    }

    // online softmax (per-lane row state)
    float mx = -INFINITY;
#pragma unroll
    for (int jt = 0; jt < 4; ++jt)
#pragma unroll
      for (int rr = 0; rr < 4; ++rr) mx = fmaxf(mx, sacc[jt][rr]);
    mx = fmaxf(mx, __shfl_xor(mx, 16));
    mx = fmaxf(mx, __shfl_xor(mx, 32));
    float mn = fmaxf(m_i, mx);
    float alpha = exp2f(m_i - mn);
    m_i = mn;
    float p[4][4], rs = 0.f;
#pragma unroll
    for (int jt = 0; jt < 4; ++jt)
#pragma unroll
      for (int rr = 0; rr < 4; ++rr) {
        float pv = exp2f(sacc[jt][rr] - mn);
        p[jt][rr] = pv; rs += pv;
      }
    rs += __shfl_xor(rs, 16);
    rs += __shfl_xor(rs, 32);
    l_i = l_i * alpha + rs;

    float a_t[4];
#pragma unroll
    for (int rr = 0; rr < 4; ++rr) a_t[rr] = __shfl(alpha, q * 4 + rr);
#pragma unroll
    for (int ht = 0; ht < 4; ++ht)
#pragma unroll
      for (int rr = 0; rr < 4; ++rr) oacc[ht][rr] *= a_t[rr];

    // P -> LDS (wave-private rows)
    {
      int row = w * 16 + l15;
#pragma unroll
      for (int jt = 0; jt < 4; ++jt) {
        ushort4 bb; bb.x = f2bf(p[jt][0]); bb.y = f2bf(p[jt][1]);
        bb.z = f2bf(p[jt][2]); bb.w = f2bf(p[jt][3]);
        *(ushort4*)&psm[row * 64 + (((2 * jt + (q >> 1)) ^ l7) << 3) + ((q & 1) << 2)] = bb;
      }
    }

    // O += P . V
#pragma unroll
    for (int ks2 = 0; ks2 < 2; ++ks2) {
      int prow = w * 16 + l15;
      bf16x8 pf = *(const bf16x8*)&psm[prow * 64 + (((q + 4 * ks2) ^ l7) << 3)];
#pragma unroll
      for (int ht = 0; ht < 4; ++ht) {
        int h = ht * 16 + l15;
        bf16x8 vf = *(const bf16x8*)&vtm[cur][h * 64 + (((q + 4 * ks2) ^ l7) << 3)];
        oacc[ht] = __builtin_amdgcn_mfma_f32_16x16x32_bf16(pf, vf, oacc[ht], 0, 0, 0);
      }
    }
  }

  if (direct) {
    float l_t[4];
#pragma unroll
    for (int rr = 0; rr < 4; ++rr) l_t[rr] = __shfl(l_i, q * 4 + rr);
#pragma unroll
    for (int rr = 0; rr < 4; ++rr) {
      float inv = 1.f / l_t[rr];
      int R = t0 + w * 16 + q * 4 + rr;
#pragma unroll
      for (int ht = 0; ht < 4; ++ht)
        out[(size_t)R * 64 + ht * 16 + l15] = oacc[ht][rr] * inv;
    }
  } else {
    const size_t slot = (size_t)(b * 16 + (qt - 16)) * 2 + ci;
    unsigned short* Op = opart + slot * 4096;
#pragma unroll
    for (int rr = 0; rr < 4; ++rr) {
      int rloc = w * 16 + q * 4 + rr;
#pragma unroll
      for (int ht = 0; ht < 4; ++ht)
        Op[rloc * 64 + ht * 16 + l15] = f2bf(oacc[ht][rr]);
    }
    if (q == 0) {
      mlpart[slot * 128 + w * 16 + l15]      = m_i;
      mlpart[slot * 128 + 64 + w * 16 + l15] = l_i;
    }
  }
}

// ============ combine: merge the two bf16 partials for qt in [16,32) ============
__global__ __launch_bounds__(256) void combine_kernel(
    const unsigned short* __restrict__ opart, const float* __restrict__ mlpart,
    float* __restrict__ out)
{
  const int qtc = blockIdx.x, b = blockIdx.y;
  const int qt = 16 + qtc;
  const int t = threadIdx.x;
  const int r = t >> 2, c0 = (t & 3) * 16;
  const size_t s0 = (size_t)(b * 16 + qtc) * 2;

  float m0 = mlpart[s0 * 128 + r],       l0 = mlpart[s0 * 128 + 64 + r];
  float m1 = mlpart[(s0 + 1) * 128 + r], l1 = mlpart[(s0 + 1) * 128 + 64 + r];
  float m  = fmaxf(m0, m1);
  float w0 = exp2f(m0 - m), w1 = exp2f(m1 - m);
  float inv = 1.f / (w0 * l0 + w1 * l1);
  w0 *= inv; w1 *= inv;

  const unsigned short* O0 = opart + s0 * 4096 + r * 64 + c0;
  const unsigned short* O1 = opart + (s0 + 1) * 4096 + r * 64 + c0;
  union { uint4 v; unsigned short e[8]; } a0, a1;
  float* op = out + (size_t)(b * TT + qt * 64 + r) * 64;
#pragma unroll
  for (int half = 0; half < 2; ++half) {
    a0.v = *(const uint4*)&O0[half * 8];
    a1.v = *(const uint4*)&O1[half * 8];
    float res[8];
#pragma unroll
    for (int u = 0; u < 8; ++u)
      res[u] = w0 * bf2f(a0.e[u]) + w1 * bf2f(a1.e[u]);
    *(float4*)&op[c0 + half * 8]     = make_float4(res[0], res[1], res[2], res[3]);
    *(float4*)&op[c0 + half * 8 + 4] = make_float4(res[4], res[5], res[6], res[7]);
  }
}

extern "C" void kernel_launch(void* const* d_in, const int* in_sizes, int n_in,
                              void* d_out, int out_size, void* d_ws, size_t ws_size,
                              hipStream_t stream) {
  const float* x  = (const float*)d_in[0];
  const float* Wk = (const float*)d_in[1];
  const float* Wq = (const float*)d_in[2];
  const float* Wv = (const float*)d_in[3];
  unsigned short* kws = (unsigned short*)d_ws;            // 4.19 MB
  unsigned short* qws = kws + (size_t)BT * NH;            // 4.19 MB
  unsigned short* vws = qws + (size_t)BT * NH;            // 4.19 MB
  unsigned short* opart = vws + (size_t)BT * NH;          // 512 slots * 8 KB = 4.19 MB
  float* mlpart = (float*)(opart + (size_t)512 * 4096);   // 256 KB  (total ~17 MB)
  float* out = (float*)d_out;

  proj_kernel<<<dim3(512, 3), 256, 0, stream>>>(x, Wk, Wq, Wv, kws, qws, vws);
  attn_partial<<<dim3(48, 16), 256, 0, stream>>>(kws, qws, vws, out, opart, mlpart);
  combine_kernel<<<dim3(16, 16), 256, 0, stream>>>(opart, mlpart, out);
}